// Round 1
// baseline (310.397 us; speedup 1.0000x reference)
//
#include <hip/hip_runtime.h>

#define NN 100000
#define EE 400000
#define STRIPS 6250          // NN/16, exact
#define WAVES_TOT 2048       // per type: 128 blocks * 16 waves
#define MARK_BLOCKS 391      // ceil((EE/4)/256)

typedef unsigned short u16;
typedef __attribute__((ext_vector_type(4))) float floatx4;
typedef __attribute__((ext_vector_type(8))) short shortx8;
typedef __attribute__((ext_vector_type(4))) unsigned short ushortx4;
typedef __attribute__((ext_vector_type(8))) unsigned short ushortx8;

__device__ __forceinline__ u16 f2bf(float f) {
    unsigned u = __float_as_uint(f);
    u += 0x7FFFu + ((u >> 16) & 1u);
    return (u16)(u >> 16);
}

// ---- fused pre-pass: degree masks (idempotent byte stores, int4 edge reads)
//      + W -> bf16 MFMA-A-frag-order pre-pack into workspace (done ONCE here
//      instead of 128 strided scalar loads + f2bf per thread in every fused2 block)
__global__ __launch_bounds__(256) void mark_conv(
    const int4* __restrict__ daa, const int4* __restrict__ dab,
    const int4* __restrict__ dba,
    const float* __restrict__ Wr0, const float* __restrict__ Wr1,
    unsigned char* __restrict__ m, u16* __restrict__ wbf) {
    const int blk = blockIdx.x;
    if (blk < MARK_BLOCKS) {
        int i = blk * 256 + threadIdx.x;
        if (i < EE / 4) {
            int4 a = daa[i], bb = dab[i], c = dba[i];
            m[a.x] = 1; m[a.y] = 1; m[a.z] = 1; m[a.w] = 1;
            m[NN + bb.x] = 1; m[NN + bb.y] = 1; m[NN + bb.z] = 1; m[NN + bb.w] = 1;
            m[2 * NN + c.x] = 1; m[2 * NN + c.y] = 1; m[2 * NN + c.z] = 1; m[2 * NN + c.w] = 1;
        }
    } else {
        // 32 blocks: 8192 threads, one ushortx8 (8 W values) each.
        // Layout matches fused2's af read: [type][mat][chunk 0..31][l2 0..63][j 0..7]
        int flat = (blk - MARK_BLOCKS) * 256 + threadIdx.x;  // [0, 8192)
        int type = flat >> 12;
        int mat = (flat >> 11) & 1;
        int chunk = (flat >> 6) & 31;
        int l2 = flat & 63;
        int kbase = (chunk >> 3) * 32 + (l2 >> 4) * 8;
        int n = (chunk & 7) * 16 + (l2 & 15);
        const float* W = (mat ? Wr1 : Wr0) + type * 16384;
        ushortx8 p;
#pragma unroll
        for (int j = 0; j < 8; ++j) p[j] = f2bf(W[(kbase + j) * 128 + n]);
        *(ushortx8*)&wbf[((type * 2 + mat) << 14) + chunk * 512 + l2 * 8] = p;
    }
}

// ---- persistent fused 2-layer, STATIC strip assignment + software pipeline.
// out[m] = relu(s^2*(z@W1) + s*b1), z = relu(feat@W0 + b0)   [relu(s*x)=s*relu(x)]
// Transposed MFMA form D = W^T x feat^T (layouts HW-verified).
// OCCUPANCY FIX vs prev: 1024 thr (16 waves) share ONE 64KB W copy ->
// 128 KB LDS, 1 block/CU, 16 waves/CU (was 8). VGPR 96 <= 128 so 4 waves/SIMD fit.
// Wave gw handles strips gw, gw+2048, ...; next strip's feat row prefetched into
// VGPRs before computing the current one (first prefetch overlaps W staging).
__global__ __launch_bounds__(1024, 4) void fused2(
    const float* __restrict__ featA, const float* __restrict__ featB,
    const u16* __restrict__ wbf,
    const float* __restrict__ br0, const float* __restrict__ br1,
    const unsigned char* __restrict__ masks, float* __restrict__ out) {
    __shared__ u16 lds[65536];   // 128 KB: [W0f 16384][W1f 16384][h1: 16 waves x 2048]

    const int type = blockIdx.x >> 7;           // 128 blocks per type
    const int bid = blockIdx.x & 127;
    const float* feat = type ? featB : featA;
    const float* b0 = br0 + type * 128;
    const float* b1 = br1 + type * 128;
    float* outp = out + (size_t)type * NN * 128;

    const int t = threadIdx.x;
    const int wave = t >> 6, lane = t & 63;
    const int quad = lane >> 4, mrow = lane & 15;
    const int gw = bid * 16 + wave;             // [0, 2048)

    // ---- prefetch strip 0 of this wave (issued BEFORE staging)
    int s = gw;
    floatx4 pf[8];
    unsigned char pm0 = 0, pm1 = 0;
    {
        const float* arow = feat + (size_t)(s * 16 + mrow) * 128;
#pragma unroll
        for (int ks = 0; ks < 4; ++ks) {
            pf[2 * ks]     = *(const floatx4*)(arow + ks * 32 + quad * 8);
            pf[2 * ks + 1] = *(const floatx4*)(arow + ks * 32 + quad * 8 + 4);
        }
        int row = s * 16 + mrow;
        if (type) pm0 = masks[NN + row];
        else { pm0 = masks[row]; pm1 = masks[2 * NN + row]; }
    }

    // ---- stage pre-packed W0f|W1f: 64 KB linear coalesced copy (already in
    //      MFMA A-frag order), 4 x 16B per thread
    {
        const ushortx8* __restrict__ wsrc = (const ushortx8*)(wbf + ((size_t)type << 15));
#pragma unroll
        for (int i = 0; i < 4; ++i) {
            int idx = i * 1024 + t;             // [0, 4096) 16B chunks
            *(ushortx8*)&lds[idx * 8] = wsrc[idx];
        }
    }
    __syncthreads();   // the only barrier

    const int h1base = 32768 + wave * 2048;

    for (;;) {
        // consume prefetch: bf16 B-frags + scale (before overwriting pf)
        shortx8 bfrag[4];
#pragma unroll
        for (int ks = 0; ks < 4; ++ks) {
            floatx4 f0 = pf[2 * ks], f1 = pf[2 * ks + 1];
            union { shortx8 v; u16 u[8]; } uu;
            uu.u[0] = f2bf(f0[0]); uu.u[1] = f2bf(f0[1]);
            uu.u[2] = f2bf(f0[2]); uu.u[3] = f2bf(f0[3]);
            uu.u[4] = f2bf(f1[0]); uu.u[5] = f2bf(f1[1]);
            uu.u[6] = f2bf(f1[2]); uu.u[7] = f2bf(f1[3]);
            bfrag[ks] = uu.v;
        }
        const float scl = type ? (1.0f + (float)pm0) * 0.5f
                               : (1.0f + (float)pm0 + (float)pm1) * (1.0f / 3.0f);
        const float s2 = scl * scl;
        const int row = s * 16 + mrow;

        // issue next strip's prefetch NOW (hidden under both GEMMs)
        const int sn = s + WAVES_TOT;
        const bool more = sn < STRIPS;
        if (more) {
            const float* arow = feat + (size_t)(sn * 16 + mrow) * 128;
#pragma unroll
            for (int ks = 0; ks < 4; ++ks) {
                pf[2 * ks]     = *(const floatx4*)(arow + ks * 32 + quad * 8);
                pf[2 * ks + 1] = *(const floatx4*)(arow + ks * 32 + quad * 8 + 4);
            }
            int nrow = sn * 16 + mrow;
            if (type) pm0 = masks[NN + nrow];
            else { pm0 = masks[nrow]; pm1 = masks[2 * NN + nrow]; }
        }

        // GEMM1: acc[nt] = W0^T tile(nt) x feat^T
        floatx4 acc[8];
#pragma unroll
        for (int nt = 0; nt < 8; ++nt) acc[nt] = (floatx4){0.f, 0.f, 0.f, 0.f};
#pragma unroll
        for (int ks = 0; ks < 4; ++ks)
#pragma unroll
            for (int nt = 0; nt < 8; ++nt) {
                shortx8 af = *(const shortx8*)&lds[((ks * 8 + nt) << 9) + lane * 8];
                acc[nt] = __builtin_amdgcn_mfma_f32_16x16x32_bf16(af, bfrag[ks], acc[nt], 0, 0, 0);
            }

        // epilogue1: z = relu(acc + b0), wave-private h1 in GEMM2 B-frag order
#pragma unroll
        for (int nt = 0; nt < 8; ++nt) {
            floatx4 bv = *(const floatx4*)(b0 + nt * 16 + quad * 4);
            ushortx4 p;
#pragma unroll
            for (int r = 0; r < 4; ++r)
                p[r] = f2bf(fmaxf(acc[nt][r] + bv[r], 0.0f));
            int q2 = (2 * nt + (quad >> 1)) & 3;
            *(ushortx4*)&lds[h1base + (nt >> 1) * 512 + q2 * 128 + mrow * 8 + (quad & 1) * 4] = p;
        }

        shortx8 h1b[4];
#pragma unroll
        for (int ks = 0; ks < 4; ++ks)
            h1b[ks] = *(const shortx8*)&lds[h1base + ks * 512 + lane * 8];

        // GEMM2: acc2[nt] = W1^T tile(nt) x z^T
        floatx4 acc2[8];
#pragma unroll
        for (int nt = 0; nt < 8; ++nt) acc2[nt] = (floatx4){0.f, 0.f, 0.f, 0.f};
#pragma unroll
        for (int ks = 0; ks < 4; ++ks)
#pragma unroll
            for (int nt = 0; nt < 8; ++nt) {
                shortx8 af = *(const shortx8*)&lds[16384 + ((ks * 8 + nt) << 9) + lane * 8];
                acc2[nt] = __builtin_amdgcn_mfma_f32_16x16x32_bf16(af, h1b[ks], acc2[nt], 0, 0, 0);
            }

        // epilogue2: out = relu(s^2*acc2 + s*b1), nontemporal (don't evict feat from L3)
        float* orow = outp + (size_t)row * 128;
#pragma unroll
        for (int nt = 0; nt < 8; ++nt) {
            floatx4 bv = *(const floatx4*)(b1 + nt * 16 + quad * 4);
            floatx4 o;
#pragma unroll
            for (int r = 0; r < 4; ++r)
                o[r] = fmaxf(s2 * acc2[nt][r] + scl * bv[r], 0.0f);
            __builtin_nontemporal_store(o, (floatx4*)(orow + nt * 16 + quad * 4));
        }

        if (!more) break;
        s = sn;
    }
}

extern "C" void kernel_launch(void* const* d_in, const int* in_sizes, int n_in,
                              void* d_out, int out_size, void* d_ws, size_t ws_size,
                              hipStream_t stream) {
    (void)in_sizes; (void)n_in; (void)out_size; (void)ws_size;
    const float* featA = (const float*)d_in[0];
    const float* featB = (const float*)d_in[1];
    const int* dst_aa = (const int*)d_in[3];
    const int* dst_ab = (const int*)d_in[5];
    const int* dst_ba = (const int*)d_in[7];
    const float* Wr0 = (const float*)d_in[10];
    const float* br0 = (const float*)d_in[11];
    const float* Wr1 = (const float*)d_in[16];
    const float* br1 = (const float*)d_in[17];

    unsigned char* masks = (unsigned char*)d_ws;              // 3*NN bytes
    u16* wbf = (u16*)((char*)d_ws + (size_t)3 * NN);          // 131072 B, 16B-aligned (300000 % 16 == 0)

    hipMemsetAsync(masks, 0, (size_t)3 * NN, stream);
    mark_conv<<<MARK_BLOCKS + 32, 256, 0, stream>>>(
        (const int4*)dst_aa, (const int4*)dst_ab, (const int4*)dst_ba,
        Wr0, Wr1, masks, wbf);
    fused2<<<256, 1024, 0, stream>>>(featA, featB, wbf, br0, br1,
                                     masks, (float*)d_out);
}

// Round 2
// 302.249 us; speedup vs baseline: 1.0270x; 1.0270x over previous
//
#include <hip/hip_runtime.h>

#define NN 100000
#define EE 400000
#define STRIPS 6250          // NN/16, exact
#define WAVES_TOT 2048       // per type: 128 blocks * 16 waves
#define MARK_BLOCKS 391      // ceil((EE/4)/256)

typedef unsigned short u16;
typedef __attribute__((ext_vector_type(4))) float floatx4;
typedef __attribute__((ext_vector_type(8))) short shortx8;
typedef __attribute__((ext_vector_type(4))) unsigned short ushortx4;
typedef __attribute__((ext_vector_type(8))) unsigned short ushortx8;

__device__ __forceinline__ u16 f2bf(float f) {
    unsigned u = __float_as_uint(f);
    u += 0x7FFFu + ((u >> 16) & 1u);
    return (u16)(u >> 16);
}

// ---- fused pre-pass: degree masks (idempotent byte stores, int4 edge reads)
//      + W -> bf16 MFMA-A-frag-order pre-pack into workspace (done ONCE here
//      instead of 128 strided scalar loads + f2bf per thread in every fused2 block)
__global__ __launch_bounds__(256) void mark_conv(
    const int4* __restrict__ daa, const int4* __restrict__ dab,
    const int4* __restrict__ dba,
    const float* __restrict__ Wr0, const float* __restrict__ Wr1,
    unsigned char* __restrict__ m, u16* __restrict__ wbf) {
    const int blk = blockIdx.x;
    if (blk < MARK_BLOCKS) {
        int i = blk * 256 + threadIdx.x;
        if (i < EE / 4) {
            int4 a = daa[i], bb = dab[i], c = dba[i];
            m[a.x] = 1; m[a.y] = 1; m[a.z] = 1; m[a.w] = 1;
            m[NN + bb.x] = 1; m[NN + bb.y] = 1; m[NN + bb.z] = 1; m[NN + bb.w] = 1;
            m[2 * NN + c.x] = 1; m[2 * NN + c.y] = 1; m[2 * NN + c.z] = 1; m[2 * NN + c.w] = 1;
        }
    } else {
        // 32 blocks: 8192 threads, one ushortx8 (8 W values) each.
        // Layout matches fused2's af read: [type][mat][chunk 0..31][l2 0..63][j 0..7]
        int flat = (blk - MARK_BLOCKS) * 256 + threadIdx.x;  // [0, 8192)
        int type = flat >> 12;
        int mat = (flat >> 11) & 1;
        int chunk = (flat >> 6) & 31;
        int l2 = flat & 63;
        int kbase = (chunk >> 3) * 32 + (l2 >> 4) * 8;
        int n = (chunk & 7) * 16 + (l2 & 15);
        const float* W = (mat ? Wr1 : Wr0) + type * 16384;
        ushortx8 p;
#pragma unroll
        for (int j = 0; j < 8; ++j) p[j] = f2bf(W[(kbase + j) * 128 + n]);
        *(ushortx8*)&wbf[((type * 2 + mat) << 14) + chunk * 512 + l2 * 8] = p;
    }
}

// ---- persistent fused 2-layer, STATIC strip assignment + software pipeline.
// out[m] = relu(s^2*(z@W1) + s*b1), z = relu(feat@W0 + b0)   [relu(s*x)=s*relu(x)]
// Transposed MFMA form D = W^T x feat^T (layouts HW-verified).
// 1024 thr (16 waves) share ONE 64KB W copy -> 128 KB LDS, 1 block/CU,
// 16 waves/CU. VGPR 64 -> no register limit on occupancy.
// NOTE (round-1 post-mortem): __builtin_nontemporal_store on the output was a
// 2.5x HBM-traffic multiplier (WRITE 100->249 MB, FETCH 51->124 MB: sub-line
// streaming stores defeat L2/L3 write-combining and force line fills).
// Plain stores let L2 assemble full output lines -> flushed once.
__global__ __launch_bounds__(1024, 4) void fused2(
    const float* __restrict__ featA, const float* __restrict__ featB,
    const u16* __restrict__ wbf,
    const float* __restrict__ br0, const float* __restrict__ br1,
    const unsigned char* __restrict__ masks, float* __restrict__ out) {
    __shared__ u16 lds[65536];   // 128 KB: [W0f 16384][W1f 16384][h1: 16 waves x 2048]

    const int type = blockIdx.x >> 7;           // 128 blocks per type
    const int bid = blockIdx.x & 127;
    const float* feat = type ? featB : featA;
    const float* b0 = br0 + type * 128;
    const float* b1 = br1 + type * 128;
    float* outp = out + (size_t)type * NN * 128;

    const int t = threadIdx.x;
    const int wave = t >> 6, lane = t & 63;
    const int quad = lane >> 4, mrow = lane & 15;
    const int gw = bid * 16 + wave;             // [0, 2048)

    // ---- prefetch strip 0 of this wave (issued BEFORE staging)
    int s = gw;
    floatx4 pf[8];
    unsigned char pm0 = 0, pm1 = 0;
    {
        const float* arow = feat + (size_t)(s * 16 + mrow) * 128;
#pragma unroll
        for (int ks = 0; ks < 4; ++ks) {
            pf[2 * ks]     = *(const floatx4*)(arow + ks * 32 + quad * 8);
            pf[2 * ks + 1] = *(const floatx4*)(arow + ks * 32 + quad * 8 + 4);
        }
        int row = s * 16 + mrow;
        if (type) pm0 = masks[NN + row];
        else { pm0 = masks[row]; pm1 = masks[2 * NN + row]; }
    }

    // ---- stage pre-packed W0f|W1f: 64 KB linear coalesced copy (already in
    //      MFMA A-frag order), 4 x 16B per thread
    {
        const ushortx8* __restrict__ wsrc = (const ushortx8*)(wbf + ((size_t)type << 15));
#pragma unroll
        for (int i = 0; i < 4; ++i) {
            int idx = i * 1024 + t;             // [0, 4096) 16B chunks
            *(ushortx8*)&lds[idx * 8] = wsrc[idx];
        }
    }
    __syncthreads();   // the only barrier

    const int h1base = 32768 + wave * 2048;

    for (;;) {
        // consume prefetch: bf16 B-frags + scale (before overwriting pf)
        shortx8 bfrag[4];
#pragma unroll
        for (int ks = 0; ks < 4; ++ks) {
            floatx4 f0 = pf[2 * ks], f1 = pf[2 * ks + 1];
            union { shortx8 v; u16 u[8]; } uu;
            uu.u[0] = f2bf(f0[0]); uu.u[1] = f2bf(f0[1]);
            uu.u[2] = f2bf(f0[2]); uu.u[3] = f2bf(f0[3]);
            uu.u[4] = f2bf(f1[0]); uu.u[5] = f2bf(f1[1]);
            uu.u[6] = f2bf(f1[2]); uu.u[7] = f2bf(f1[3]);
            bfrag[ks] = uu.v;
        }
        const float scl = type ? (1.0f + (float)pm0) * 0.5f
                               : (1.0f + (float)pm0 + (float)pm1) * (1.0f / 3.0f);
        const float s2 = scl * scl;
        const int row = s * 16 + mrow;

        // issue next strip's prefetch NOW (hidden under both GEMMs)
        const int sn = s + WAVES_TOT;
        const bool more = sn < STRIPS;
        if (more) {
            const float* arow = feat + (size_t)(sn * 16 + mrow) * 128;
#pragma unroll
            for (int ks = 0; ks < 4; ++ks) {
                pf[2 * ks]     = *(const floatx4*)(arow + ks * 32 + quad * 8);
                pf[2 * ks + 1] = *(const floatx4*)(arow + ks * 32 + quad * 8 + 4);
            }
            int nrow = sn * 16 + mrow;
            if (type) pm0 = masks[NN + nrow];
            else { pm0 = masks[nrow]; pm1 = masks[2 * NN + nrow]; }
        }

        // GEMM1: acc[nt] = W0^T tile(nt) x feat^T
        floatx4 acc[8];
#pragma unroll
        for (int nt = 0; nt < 8; ++nt) acc[nt] = (floatx4){0.f, 0.f, 0.f, 0.f};
#pragma unroll
        for (int ks = 0; ks < 4; ++ks)
#pragma unroll
            for (int nt = 0; nt < 8; ++nt) {
                shortx8 af = *(const shortx8*)&lds[((ks * 8 + nt) << 9) + lane * 8];
                acc[nt] = __builtin_amdgcn_mfma_f32_16x16x32_bf16(af, bfrag[ks], acc[nt], 0, 0, 0);
            }

        // epilogue1: z = relu(acc + b0), wave-private h1 in GEMM2 B-frag order
#pragma unroll
        for (int nt = 0; nt < 8; ++nt) {
            floatx4 bv = *(const floatx4*)(b0 + nt * 16 + quad * 4);
            ushortx4 p;
#pragma unroll
            for (int r = 0; r < 4; ++r)
                p[r] = f2bf(fmaxf(acc[nt][r] + bv[r], 0.0f));
            int q2 = (2 * nt + (quad >> 1)) & 3;
            *(ushortx4*)&lds[h1base + (nt >> 1) * 512 + q2 * 128 + mrow * 8 + (quad & 1) * 4] = p;
        }

        shortx8 h1b[4];
#pragma unroll
        for (int ks = 0; ks < 4; ++ks)
            h1b[ks] = *(const shortx8*)&lds[h1base + ks * 512 + lane * 8];

        // GEMM2: acc2[nt] = W1^T tile(nt) x z^T
        floatx4 acc2[8];
#pragma unroll
        for (int nt = 0; nt < 8; ++nt) acc2[nt] = (floatx4){0.f, 0.f, 0.f, 0.f};
#pragma unroll
        for (int ks = 0; ks < 4; ++ks)
#pragma unroll
            for (int nt = 0; nt < 8; ++nt) {
                shortx8 af = *(const shortx8*)&lds[16384 + ((ks * 8 + nt) << 9) + lane * 8];
                acc2[nt] = __builtin_amdgcn_mfma_f32_16x16x32_bf16(af, h1b[ks], acc2[nt], 0, 0, 0);
            }

        // epilogue2: out = relu(s^2*acc2 + s*b1), plain stores (L2 write-combines)
        float* orow = outp + (size_t)row * 128;
#pragma unroll
        for (int nt = 0; nt < 8; ++nt) {
            floatx4 bv = *(const floatx4*)(b1 + nt * 16 + quad * 4);
            floatx4 o;
#pragma unroll
            for (int r = 0; r < 4; ++r)
                o[r] = fmaxf(s2 * acc2[nt][r] + scl * bv[r], 0.0f);
            *(floatx4*)(orow + nt * 16 + quad * 4) = o;
        }

        if (!more) break;
        s = sn;
    }
}

extern "C" void kernel_launch(void* const* d_in, const int* in_sizes, int n_in,
                              void* d_out, int out_size, void* d_ws, size_t ws_size,
                              hipStream_t stream) {
    (void)in_sizes; (void)n_in; (void)out_size; (void)ws_size;
    const float* featA = (const float*)d_in[0];
    const float* featB = (const float*)d_in[1];
    const int* dst_aa = (const int*)d_in[3];
    const int* dst_ab = (const int*)d_in[5];
    const int* dst_ba = (const int*)d_in[7];
    const float* Wr0 = (const float*)d_in[10];
    const float* br0 = (const float*)d_in[11];
    const float* Wr1 = (const float*)d_in[16];
    const float* br1 = (const float*)d_in[17];

    unsigned char* masks = (unsigned char*)d_ws;              // 3*NN bytes
    u16* wbf = (u16*)((char*)d_ws + (size_t)3 * NN);          // 131072 B, 16B-aligned (300000 % 16 == 0)

    hipMemsetAsync(masks, 0, (size_t)3 * NN, stream);
    mark_conv<<<MARK_BLOCKS + 32, 256, 0, stream>>>(
        (const int4*)dst_aa, (const int4*)dst_ab, (const int4*)dst_ba,
        Wr0, Wr1, masks, wbf);
    fused2<<<256, 1024, 0, stream>>>(featA, featB, wbf, br0, br1,
                                     masks, (float*)d_out);
}

// Round 4
// 291.707 us; speedup vs baseline: 1.0641x; 1.0361x over previous
//
#include <hip/hip_runtime.h>

#define NN 100000
#define EE 400000
#define STRIPS 6250          // NN/16, exact
#define WAVES_TOT 2048       // per type: 128 blocks * 16 waves
#define MARK_BLOCKS 391      // ceil((EE/4)/256)

typedef unsigned short u16;
typedef __attribute__((ext_vector_type(4))) float floatx4;
typedef __attribute__((ext_vector_type(8))) short shortx8;
typedef __attribute__((ext_vector_type(4))) unsigned short ushortx4;
typedef __attribute__((ext_vector_type(8))) unsigned short ushortx8;

__device__ __forceinline__ u16 f2bf(float f) {
    unsigned u = __float_as_uint(f);
    u += 0x7FFFu + ((u >> 16) & 1u);
    return (u16)(u >> 16);
}

// ---- fused pre-pass: degree masks (idempotent byte stores, int4 edge reads)
//      + W -> bf16 MFMA-A-frag-order pre-pack into workspace
__global__ __launch_bounds__(256) void mark_conv(
    const int4* __restrict__ daa, const int4* __restrict__ dab,
    const int4* __restrict__ dba,
    const float* __restrict__ Wr0, const float* __restrict__ Wr1,
    unsigned char* __restrict__ m, u16* __restrict__ wbf) {
    const int blk = blockIdx.x;
    if (blk < MARK_BLOCKS) {
        int i = blk * 256 + threadIdx.x;
        if (i < EE / 4) {
            int4 a = daa[i], bb = dab[i], c = dba[i];
            m[a.x] = 1; m[a.y] = 1; m[a.z] = 1; m[a.w] = 1;
            m[NN + bb.x] = 1; m[NN + bb.y] = 1; m[NN + bb.z] = 1; m[NN + bb.w] = 1;
            m[2 * NN + c.x] = 1; m[2 * NN + c.y] = 1; m[2 * NN + c.z] = 1; m[2 * NN + c.w] = 1;
        }
    } else {
        // 32 blocks: 8192 threads, one ushortx8 (8 W values) each.
        // Layout matches fused2's af read: [type][mat][chunk 0..31][l2 0..63][j 0..7]
        int flat = (blk - MARK_BLOCKS) * 256 + threadIdx.x;  // [0, 8192)
        int type = flat >> 12;
        int mat = (flat >> 11) & 1;
        int chunk = (flat >> 6) & 31;
        int l2 = flat & 63;
        int kbase = (chunk >> 3) * 32 + (l2 >> 4) * 8;
        int n = (chunk & 7) * 16 + (l2 & 15);
        const float* W = (mat ? Wr1 : Wr0) + type * 16384;
        ushortx8 p;
#pragma unroll
        for (int j = 0; j < 8; ++j) p[j] = f2bf(W[(kbase + j) * 128 + n]);
        *(ushortx8*)&wbf[((type * 2 + mat) << 14) + chunk * 512 + l2 * 8] = p;
    }
}

// ---- persistent fused 2-layer, STATIC strip assignment + software pipeline.
// out[m] = relu(s^2*(z@W1) + s*b1), z = relu(feat@W0 + b0)   [relu(s*x)=s*relu(x)]
// Transposed MFMA form D = W^T x feat^T (layouts HW-verified).
// 1024 thr (16 waves) share ONE 64KB W copy -> 128 KB LDS, 1 block/CU, 16 waves/CU.
//
// ROUND-2 POST-MORTEM: at 16 waves/CU the epilogue's two 64B-per-line store
// instructions left a partial-line window; L2 (4MB/XCD = in-flight dirty)
// evicted half-written lines -> fetch-merge + double writeback
// (WRITE 100->220 MB, FETCH 51->140 MB). FIX: stage output via the dead h1
// LDS buffer, store 1 KB fully contiguous per instruction (8 complete lines).
// ROUND-3 POST-MORTEM: the first staging attempt let the compiler MERGE the
// per-chunk conditional ds_writes (identical addr+data, disjoint predicates)
// into one unconditional store -> intra-wave race -> wrong results. Phases
// must be separated by asm memory fences with explicit lgkmcnt(0); intra-wave
// lockstep is NOT a memory-ordering guarantee the compiler respects.
__global__ __launch_bounds__(1024, 4) void fused2(
    const float* __restrict__ featA, const float* __restrict__ featB,
    const u16* __restrict__ wbf,
    const float* __restrict__ br0, const float* __restrict__ br1,
    const unsigned char* __restrict__ masks, float* __restrict__ out) {
    __shared__ u16 lds[65536];   // 128 KB: [W0f 16384][W1f 16384][h1/ostage: 16 waves x 4096 B]

    const int type = blockIdx.x >> 7;           // 128 blocks per type
    const int bid = blockIdx.x & 127;
    const float* feat = type ? featB : featA;
    const float* b0 = br0 + type * 128;
    const float* b1 = br1 + type * 128;
    float* outp = out + (size_t)type * NN * 128;

    const int t = threadIdx.x;
    const int wave = t >> 6, lane = t & 63;
    const int quad = lane >> 4, mrow = lane & 15;
    const int gw = bid * 16 + wave;             // [0, 2048)

    // ---- prefetch strip 0 of this wave (issued BEFORE staging)
    int s = gw;
    floatx4 pf[8];
    unsigned char pm0 = 0, pm1 = 0;
    {
        const float* arow = feat + (size_t)(s * 16 + mrow) * 128;
#pragma unroll
        for (int ks = 0; ks < 4; ++ks) {
            pf[2 * ks]     = *(const floatx4*)(arow + ks * 32 + quad * 8);
            pf[2 * ks + 1] = *(const floatx4*)(arow + ks * 32 + quad * 8 + 4);
        }
        int row = s * 16 + mrow;
        if (type) pm0 = masks[NN + row];
        else { pm0 = masks[row]; pm1 = masks[2 * NN + row]; }
    }

    // ---- stage pre-packed W0f|W1f: 64 KB linear coalesced copy (already in
    //      MFMA A-frag order), 4 x 16B per thread
    {
        const ushortx8* __restrict__ wsrc = (const ushortx8*)(wbf + ((size_t)type << 15));
#pragma unroll
        for (int i = 0; i < 4; ++i) {
            int idx = i * 1024 + t;             // [0, 4096) 16B chunks
            *(ushortx8*)&lds[idx * 8] = wsrc[idx];
        }
    }
    __syncthreads();   // the only barrier

    const int h1base = 32768 + wave * 2048;     // u16 index; 4096 B per wave

    for (;;) {
        // consume prefetch: bf16 B-frags + scale (before overwriting pf)
        shortx8 bfrag[4];
#pragma unroll
        for (int ks = 0; ks < 4; ++ks) {
            floatx4 f0 = pf[2 * ks], f1 = pf[2 * ks + 1];
            union { shortx8 v; u16 u[8]; } uu;
            uu.u[0] = f2bf(f0[0]); uu.u[1] = f2bf(f0[1]);
            uu.u[2] = f2bf(f0[2]); uu.u[3] = f2bf(f0[3]);
            uu.u[4] = f2bf(f1[0]); uu.u[5] = f2bf(f1[1]);
            uu.u[6] = f2bf(f1[2]); uu.u[7] = f2bf(f1[3]);
            bfrag[ks] = uu.v;
        }
        const float scl = type ? (1.0f + (float)pm0) * 0.5f
                               : (1.0f + (float)pm0 + (float)pm1) * (1.0f / 3.0f);
        const float s2 = scl * scl;

        // issue next strip's prefetch NOW (hidden under both GEMMs)
        const int sn = s + WAVES_TOT;
        const bool more = sn < STRIPS;
        if (more) {
            const float* arow = feat + (size_t)(sn * 16 + mrow) * 128;
#pragma unroll
            for (int ks = 0; ks < 4; ++ks) {
                pf[2 * ks]     = *(const floatx4*)(arow + ks * 32 + quad * 8);
                pf[2 * ks + 1] = *(const floatx4*)(arow + ks * 32 + quad * 8 + 4);
            }
            int nrow = sn * 16 + mrow;
            if (type) pm0 = masks[NN + nrow];
            else { pm0 = masks[nrow]; pm1 = masks[2 * NN + nrow]; }
        }

        // GEMM1: acc[nt] = W0^T tile(nt) x feat^T
        floatx4 acc[8];
#pragma unroll
        for (int nt = 0; nt < 8; ++nt) acc[nt] = (floatx4){0.f, 0.f, 0.f, 0.f};
#pragma unroll
        for (int ks = 0; ks < 4; ++ks)
#pragma unroll
            for (int nt = 0; nt < 8; ++nt) {
                shortx8 af = *(const shortx8*)&lds[((ks * 8 + nt) << 9) + lane * 8];
                acc[nt] = __builtin_amdgcn_mfma_f32_16x16x32_bf16(af, bfrag[ks], acc[nt], 0, 0, 0);
            }

        // epilogue1: z = relu(acc + b0), wave-private h1 in GEMM2 B-frag order
#pragma unroll
        for (int nt = 0; nt < 8; ++nt) {
            floatx4 bv = *(const floatx4*)(b0 + nt * 16 + quad * 4);
            ushortx4 p;
#pragma unroll
            for (int r = 0; r < 4; ++r)
                p[r] = f2bf(fmaxf(acc[nt][r] + bv[r], 0.0f));
            int q2 = (2 * nt + (quad >> 1)) & 3;
            *(ushortx4*)&lds[h1base + (nt >> 1) * 512 + q2 * 128 + mrow * 8 + (quad & 1) * 4] = p;
        }

        shortx8 h1b[4];
#pragma unroll
        for (int ks = 0; ks < 4; ++ks)
            h1b[ks] = *(const shortx8*)&lds[h1base + ks * 512 + lane * 8];
        // (h1 buffer is dead from here on -> reused below as output staging)

        // GEMM2: acc2[nt] = W1^T tile(nt) x z^T
        floatx4 acc2[8];
#pragma unroll
        for (int nt = 0; nt < 8; ++nt) acc2[nt] = (floatx4){0.f, 0.f, 0.f, 0.f};
#pragma unroll
        for (int ks = 0; ks < 4; ++ks)
#pragma unroll
            for (int nt = 0; nt < 8; ++nt) {
                shortx8 af = *(const shortx8*)&lds[16384 + ((ks * 8 + nt) << 9) + lane * 8];
                acc2[nt] = __builtin_amdgcn_mfma_f32_16x16x32_bf16(af, h1b[ks], acc2[nt], 0, 0, 0);
            }

        // epilogue2: o = relu(s^2*acc2 + s*b1) into regs
        floatx4 o[8];
#pragma unroll
        for (int nt = 0; nt < 8; ++nt) {
            floatx4 bv = *(const floatx4*)(b1 + nt * 16 + quad * 4);
#pragma unroll
            for (int r = 0; r < 4; ++r)
                o[nt][r] = fmaxf(s2 * acc2[nt][r] + scl * bv[r], 0.0f);
        }

        // output via wave-private LDS staging, 2 phases x 8 rows (4096 B each):
        // owning half-wave scatters its 32 floats/lane, fence, then all 64
        // lanes read back linearly and store 1 KB contiguous per instruction
        // (8 complete 128B lines per store -> no partial-line window).
        {
            float* ostage = (float*)&lds[h1base];            // 4096 B, dead h1 buffer
            float* sbase = outp + (size_t)(s * 16) * 128;    // strip base (rows contiguous)
            const int r8 = mrow & 7, pmine = mrow >> 3;
#pragma unroll
            for (int p = 0; p < 2; ++p) {
                if (pmine == p) {
#pragma unroll
                    for (int nt = 0; nt < 8; ++nt)
                        *(floatx4*)&ostage[r8 * 128 + nt * 16 + quad * 4] = o[nt];
                }
                // fence: writes complete + no compile-time motion across
                asm volatile("s_waitcnt lgkmcnt(0)" ::: "memory");
                __builtin_amdgcn_sched_barrier(0);
                floatx4 w[4];
#pragma unroll
                for (int i = 0; i < 4; ++i)
                    w[i] = *(const floatx4*)&ostage[i * 256 + lane * 4];
                // fence: reads returned before next phase's writes
                asm volatile("s_waitcnt lgkmcnt(0)" ::: "memory");
                __builtin_amdgcn_sched_barrier(0);
#pragma unroll
                for (int i = 0; i < 4; ++i)
                    *(floatx4*)(sbase + p * 1024 + i * 256 + lane * 4) = w[i];
            }
        }

        if (!more) break;
        s = sn;
    }
}

extern "C" void kernel_launch(void* const* d_in, const int* in_sizes, int n_in,
                              void* d_out, int out_size, void* d_ws, size_t ws_size,
                              hipStream_t stream) {
    (void)in_sizes; (void)n_in; (void)out_size; (void)ws_size;
    const float* featA = (const float*)d_in[0];
    const float* featB = (const float*)d_in[1];
    const int* dst_aa = (const int*)d_in[3];
    const int* dst_ab = (const int*)d_in[5];
    const int* dst_ba = (const int*)d_in[7];
    const float* Wr0 = (const float*)d_in[10];
    const float* br0 = (const float*)d_in[11];
    const float* Wr1 = (const float*)d_in[16];
    const float* br1 = (const float*)d_in[17];

    unsigned char* masks = (unsigned char*)d_ws;              // 3*NN bytes
    u16* wbf = (u16*)((char*)d_ws + (size_t)3 * NN);          // 131072 B, 16B-aligned (300000 % 16 == 0)

    hipMemsetAsync(masks, 0, (size_t)3 * NN, stream);
    mark_conv<<<MARK_BLOCKS + 32, 256, 0, stream>>>(
        (const int4*)dst_aa, (const int4*)dst_ab, (const int4*)dst_ba,
        Wr0, Wr1, masks, wbf);
    fused2<<<256, 1024, 0, stream>>>(featA, featB, wbf, br0, br1,
                                     masks, (float*)d_out);
}